// Round 10
// baseline (453.094 us; speedup 1.0000x reference)
//
#include <hip/hip_runtime.h>

#define N_NODES 50000
#define HIDDEN  64
#define N_EDGES 1200000

#define BSHIFT 7                       // 128 nodes per bucket
#define BUKSZ  128
#define NBUK   391                     // ceil(50000/128)
#define ABLK   512                     // block-local-sort blocks
#define CH     2344                    // ceil(N_EDGES/ABLK)
#define PAD2   4096                    // csr capacity per bucket (avg 3072 + 4-align pad)
#define FWAVES 12500                   // fused-layer waves (1 node per wave-iteration)
#define FBLK   (FWAVES / 4)            // 3125 blocks
#define NPW    4                       // nodes per wave (strided)
#define WLD    65                      // LDS W row stride (floats): 16-row groups -> 2-way only

typedef unsigned short ushort_t;

__device__ __forceinline__ float bcastf(float v, int k) {
    return __int_as_float(__builtin_amdgcn_readlane(__float_as_int(v), k));
}
__device__ __forceinline__ unsigned f2bf(float x) {    // f32 -> bf16 RNE
    unsigned u = __float_as_uint(x);
    u += 0x7fffu + ((u >> 16) & 1u);
    return u >> 16;
}
__device__ __forceinline__ float bfl(unsigned w) { return __uint_as_float(w << 16); }
__device__ __forceinline__ float bfh(unsigned w) { return __uint_as_float(w & 0xffff0000u); }
__device__ __forceinline__ void bfly(float4& a) {      // all lanes end with group-sum
    a.x += __shfl_xor(a.x, 16); a.y += __shfl_xor(a.y, 16);
    a.z += __shfl_xor(a.z, 16); a.w += __shfl_xor(a.w, 16);
    a.x += __shfl_xor(a.x, 32); a.y += __shfl_xor(a.y, 32);
    a.z += __shfl_xor(a.z, 32); a.w += __shfl_xor(a.w, 32);
}

// ---------------- Kernel A: block-local bucket sort (pure stores) ----------------
__global__ __launch_bounds__(512) void build_a_kernel(const int* __restrict__ ei,
                                                      int* __restrict__ tmp,
                                                      int* __restrict__ starts_m,
                                                      int* __restrict__ counts_m) {
    __shared__ int hist[NBUK];
    __shared__ int cur[NBUK];
    __shared__ int stage[CH];
    int b = blockIdx.x, tid = threadIdx.x;
    int base = b * CH;
    int cnt = N_EDGES - base; if (cnt > CH) cnt = CH;
    for (int i = tid; i < NBUK; i += 512) hist[i] = 0;
    __syncthreads();
    for (int i = tid; i < cnt; i += 512)
        atomicAdd(&hist[ei[N_EDGES + base + i] >> BSHIFT], 1);
    __syncthreads();
    int v = (tid < NBUK) ? hist[tid] : 0;
#pragma unroll
    for (int o = 1; o < NBUK; o <<= 1) {
        __syncthreads();
        int y = (tid >= o && tid < NBUK) ? hist[tid - o] : 0;
        __syncthreads();
        if (tid < NBUK) hist[tid] += y;
    }
    __syncthreads();
    if (tid < NBUK) {
        int excl = hist[tid] - v;
        cur[tid] = excl;
        starts_m[tid * ABLK + b] = base + excl;
        counts_m[tid * ABLK + b] = v;
    }
    __syncthreads();
    for (int i = tid; i < cnt; i += 512) {
        int src = ei[base + i];
        int dst = ei[N_EDGES + base + i];
        int p = atomicAdd(&cur[dst >> BSHIFT], 1);
        stage[p] = src | ((dst & (BUKSZ - 1)) << 16);
    }
    __syncthreads();
    for (int i = tid; i < cnt; i += 512) tmp[base + i] = stage[i];
}

// ---------------- Kernel B: per-bucket counting sort (4-aligned) + gemm1 ----------------
__global__ __launch_bounds__(512) void build_b_kernel(const int* __restrict__ tmp,
                                                      const int* __restrict__ starts_m,
                                                      const int* __restrict__ counts_m,
                                                      int2* __restrict__ row_info,
                                                      ushort_t* __restrict__ csr,
                                                      const float* __restrict__ x,
                                                      const float* __restrict__ Wrel,
                                                      const float* __restrict__ Wroot,
                                                      const float* __restrict__ bias,
                                                      ushort_t* __restrict__ tbf,
                                                      ushort_t* __restrict__ ubf) {
    __shared__ int sl[ABLK];
    __shared__ int cl[ABLK];
    __shared__ int hist[BUKSZ];
    __shared__ int cur[BUKSZ];
    __shared__ ushort_t stage[PAD2];
    int b = blockIdx.x, tid = threadIdx.x;
    if (b < NBUK) {
        sl[tid] = starts_m[b * ABLK + tid];
        cl[tid] = counts_m[b * ABLK + tid];
        if (tid < BUKSZ) hist[tid] = 0;
        __syncthreads();
        {   // thread-per-segment histogram
            int s = sl[tid], c = cl[tid];
            for (int i = 0; i < c; ++i) atomicAdd(&hist[tmp[s + i] >> 16], 1);
        }
        __syncthreads();
        int v = (tid < BUKSZ) ? hist[tid] : 0;
        int vr = (v + 3) & ~3;                 // 4-aligned per-node segment
        __syncthreads();
        if (tid < BUKSZ) hist[tid] = vr;
#pragma unroll
        for (int o = 1; o < BUKSZ; o <<= 1) {
            __syncthreads();
            int y = (tid >= o && tid < BUKSZ) ? hist[tid - o] : 0;
            __syncthreads();
            if (tid < BUKSZ) hist[tid] += y;
        }
        __syncthreads();
        if (tid < BUKSZ) {
            int excl = hist[tid] - vr;
            cur[tid] = excl;
            int node = (b << BSHIFT) + tid;
            if (node < N_NODES) row_info[node] = make_int2(b * PAD2 + excl, v);
        }
        __syncthreads();
        {   // thread-per-segment placement
            int s = sl[tid], c = cl[tid];
            for (int i = 0; i < c; ++i) {
                int p = tmp[s + i];
                int slot = atomicAdd(&cur[p >> 16], 1);
                stage[slot] = (ushort_t)(p & 0xFFFF);
            }
        }
        __syncthreads();
        int total = hist[BUKSZ - 1];           // rounded; pad slots garbage (clamped on use)
        for (int i = tid; i < total; i += 512) csr[b * PAD2 + i] = stage[i];
    } else {
        // gemm1: t1 = x@Wrel (bf16), u1 = x@Wroot + b1 (bf16)
        int lane = tid & 63;
        float wn[64], ws[64];
#pragma unroll
        for (int k = 0; k < 64; ++k) {
            wn[k] = Wrel[k * 64 + lane];
            ws[k] = Wroot[k * 64 + lane];
        }
        float bv = bias[lane];
        int wave = (b - NBUK) * 8 + (tid >> 6);
        int nwaves = (gridDim.x - NBUK) * 8;
        if (wave == 0) tbf[(size_t)N_NODES * 64 + lane] = 0;   // zero clamp row
        for (int i = wave; i < N_NODES; i += nwaves) {
            float hv = x[i * 64 + lane];
            float tacc = 0.f, uacc = bv;
#pragma unroll
            for (int k = 0; k < 64; ++k) {
                float hk = bcastf(hv, k);
                tacc = fmaf(hk, wn[k], tacc);
                uacc = fmaf(hk, ws[k], uacc);
            }
            tbf[(size_t)i * 64 + lane] = (ushort_t)f2bf(tacc);
            ubf[(size_t)i * 64 + lane] = (ushort_t)f2bf(uacc);
        }
    }
}

// ---------------- shfl-free gather-aggregate for one node (R8-proven) ----------------
__device__ __forceinline__ float4 agg_core(const ushort_t* __restrict__ tbf,
                                           const ushort_t* __restrict__ csr,
                                           int start, int deg, int g, int q) {
    const ushort_t* cp = csr + start;          // start is 4-aligned
    float4 a0{0,0,0,0}, a1{0,0,0,0}, a2{0,0,0,0}, a3{0,0,0,0};
    for (int base = 0; base < deg; base += 16) {
        int m = base + 4 * g;
        const uint2 iv = *(const uint2*)(cp + m);
        int s0 = (m + 0 < deg) ? (int)(iv.x & 0xFFFF) : N_NODES;
        int s1 = (m + 1 < deg) ? (int)(iv.x >> 16)    : N_NODES;
        int s2 = (m + 2 < deg) ? (int)(iv.y & 0xFFFF) : N_NODES;
        int s3 = (m + 3 < deg) ? (int)(iv.y >> 16)    : N_NODES;
        const uint2 w0 = *(const uint2*)(tbf + (size_t)s0 * 64 + q * 4);
        const uint2 w1 = *(const uint2*)(tbf + (size_t)s1 * 64 + q * 4);
        const uint2 w2 = *(const uint2*)(tbf + (size_t)s2 * 64 + q * 4);
        const uint2 w3 = *(const uint2*)(tbf + (size_t)s3 * 64 + q * 4);
        a0.x += bfl(w0.x); a0.y += bfh(w0.x); a0.z += bfl(w0.y); a0.w += bfh(w0.y);
        a1.x += bfl(w1.x); a1.y += bfh(w1.x); a1.z += bfl(w1.y); a1.w += bfh(w1.y);
        a2.x += bfl(w2.x); a2.y += bfh(w2.x); a2.z += bfl(w2.y); a2.w += bfh(w2.y);
        a3.x += bfl(w3.x); a3.y += bfh(w3.x); a3.z += bfl(w3.y); a3.w += bfh(w3.y);
    }
    float4 acc;
    acc.x = (a0.x + a1.x) + (a2.x + a3.x);
    acc.y = (a0.y + a1.y) + (a2.y + a3.y);
    acc.z = (a0.z + a1.z) + (a2.z + a3.z);
    acc.w = (a0.w + a1.w) + (a2.w + a3.w);
    bfly(acc);
    return acc;
}

__device__ __forceinline__ float4 unpack_u(const ushort_t* __restrict__ ubf, int node, int q) {
    const uint2 uv = *(const uint2*)(ubf + (size_t)node * 64 + q * 4);
    return make_float4(bfl(uv.x), bfh(uv.x), bfl(uv.y), bfh(uv.y));
}

// ---------------- fused: agg(layer k) [+ dout] + gemm(layer k+1), f32 W in LDS ----------------
__global__ __launch_bounds__(256, 4) void fused_kernel(const ushort_t* __restrict__ tin,
                                                       const ushort_t* __restrict__ uin,
                                                       const int2* __restrict__ row_info,
                                                       const ushort_t* __restrict__ csr,
                                                       const float* __restrict__ Wn,
                                                       const float* __restrict__ Ws,
                                                       const float* __restrict__ bias_next,
                                                       ushort_t* __restrict__ tout,
                                                       ushort_t* __restrict__ uout,
                                                       float* __restrict__ dout,
                                                       int use_mean) {
    __shared__ float wn_lds[64 * WLD];   // 16.6 KB, row-padded: 16-row groups alias 2-way (free)
    __shared__ float ws_lds[64 * WLD];
    __shared__ float blds[64];
    int tid = threadIdx.x;
    for (int i = tid; i < 4096; i += 256) {
        int k = i >> 6, j = i & 63;
        wn_lds[k * WLD + j] = Wn[i];
        ws_lds[k * WLD + j] = Ws[i];
    }
    if (tid < 64) blds[tid] = bias_next[tid];
    if (blockIdx.x == 0 && tid < 32)       // zero clamp row of tout (128 B)
        ((unsigned*)(tout + (size_t)N_NODES * 64))[tid] = 0;
    __syncthreads();
    int lane = tid & 63, g = lane >> 4, q = lane & 15;
    int w = blockIdx.x * 4 + (tid >> 6);

#pragma unroll
    for (int i = 0; i < NPW; ++i) {
        int node = w + FWAVES * i;
        if (node >= N_NODES) continue;
        int2 ri = row_info[node];
        float4 acc = agg_core(tin, csr, ri.x, ri.y, g, q);
        float sc = use_mean ? 1.f / fmaxf((float)ri.y, 1.f) : 1.f;
        const float4 uv = unpack_u(uin, node, q);
        float4 h;
        h.x = fmaxf(uv.x + acc.x * sc, 0.f);
        h.y = fmaxf(uv.y + acc.y * sc, 0.f);
        h.z = fmaxf(uv.z + acc.z * sc, 0.f);
        h.w = fmaxf(uv.w + acc.w * sc, 0.f);
        if (dout && g == 0)
            *(float4*)(dout + (size_t)node * 64 + q * 4) = h;
        // gemm: group g covers k in [16g,16g+16); h_k lives in lane 4g+(j>>2)
        float4 tp{0,0,0,0}, up{0,0,0,0};
#pragma unroll
        for (int j = 0; j < 16; ++j) {
            int row = 16 * g + j;
            const float4 wv_n = *(const float4*)&wn_lds[row * WLD + q * 4];
            const float4 wv_s = *(const float4*)&ws_lds[row * WLD + q * 4];
            int srcl = 4 * g + (j >> 2);
            float hk;
            if ((j & 3) == 0)      hk = __shfl(h.x, srcl);
            else if ((j & 3) == 1) hk = __shfl(h.y, srcl);
            else if ((j & 3) == 2) hk = __shfl(h.z, srcl);
            else                   hk = __shfl(h.w, srcl);
            tp.x = fmaf(hk, wv_n.x, tp.x); tp.y = fmaf(hk, wv_n.y, tp.y);
            tp.z = fmaf(hk, wv_n.z, tp.z); tp.w = fmaf(hk, wv_n.w, tp.w);
            up.x = fmaf(hk, wv_s.x, up.x); up.y = fmaf(hk, wv_s.y, up.y);
            up.z = fmaf(hk, wv_s.z, up.z); up.w = fmaf(hk, wv_s.w, up.w);
        }
        bfly(tp); bfly(up);
        if (g == 0) {
            const float4 bv = *(const float4*)&blds[q * 4];
            uint2 upk, tpk;
            upk.x = f2bf(up.x + bv.x) | (f2bf(up.y + bv.y) << 16);
            upk.y = f2bf(up.z + bv.z) | (f2bf(up.w + bv.w) << 16);
            tpk.x = f2bf(tp.x) | (f2bf(tp.y) << 16);
            tpk.y = f2bf(tp.z) | (f2bf(tp.w) << 16);
            *(uint2*)(uout + (size_t)node * 64 + q * 4) = upk;
            *(uint2*)(tout + (size_t)node * 64 + q * 4) = tpk;
        }
    }
}

// ---------------- final agg-only (R8-proven) ----------------
__global__ __launch_bounds__(256, 8) void agg_kernel(const ushort_t* __restrict__ tbf,
                                                     const ushort_t* __restrict__ ubf,
                                                     const int2* __restrict__ row_info,
                                                     const ushort_t* __restrict__ csr,
                                                     float* __restrict__ out, int use_mean) {
    int lane = threadIdx.x & 63;
    int g = lane >> 4, q = lane & 15;
    int node = (blockIdx.x * 256 + threadIdx.x) >> 6;
    if (node >= N_NODES) return;
    int2 ri = row_info[node];
    float4 acc = agg_core(tbf, csr, ri.x, ri.y, g, q);
    float scale = use_mean ? 1.f / fmaxf((float)ri.y, 1.f) : 1.f;
    if (g == 0) {
        const float4 uv = unpack_u(ubf, node, q);
        float4 r;
        r.x = fmaxf(uv.x + acc.x * scale, 0.f);
        r.y = fmaxf(uv.y + acc.y * scale, 0.f);
        r.z = fmaxf(uv.z + acc.z * scale, 0.f);
        r.w = fmaxf(uv.w + acc.w * scale, 0.f);
        *(float4*)(out + (size_t)node * 64 + q * 4) = r;
    }
}

// ---------------- launch: 6 dispatches ----------------
extern "C" void kernel_launch(void* const* d_in, const int* in_sizes, int n_in,
                              void* d_out, int out_size, void* d_ws, size_t ws_size,
                              hipStream_t stream) {
    const float* x      = (const float*)d_in[0];
    const int*   ei     = (const int*)d_in[1];
    const float* Wrel1  = (const float*)d_in[2];
    const float* Wroot1 = (const float*)d_in[3];
    const float* b1     = (const float*)d_in[4];
    const float* Wself2 = (const float*)d_in[5];
    const float* Wnbr2  = (const float*)d_in[6];
    const float* b2     = (const float*)d_in[7];
    const float* Wself3 = (const float*)d_in[8];
    const float* Wnbr3  = (const float*)d_in[9];
    const float* b3     = (const float*)d_in[10];
    const float* Wself4 = (const float*)d_in[11];
    const float* Wnbr4  = (const float*)d_in[12];
    const float* b4     = (const float*)d_in[13];

    const int N = N_NODES;

    auto align = [](size_t o) { return (o + 255) & ~(size_t)255; };
    char* base = (char*)d_ws;
    size_t off = 0;
    int*  tmp      = (int*)(base + off);  off = align(off + (size_t)ABLK * CH * 4);
    int*  starts_m = (int*)(base + off);  off = align(off + (size_t)NBUK * ABLK * 4);
    int*  counts_m = (int*)(base + off);  off = align(off + (size_t)NBUK * ABLK * 4);
    int2* row_info = (int2*)(base + off); off = align(off + (size_t)N * 8);
    ushort_t* csr  = (ushort_t*)(base + off); off = align(off + (size_t)NBUK * PAD2 * 2 + 256);
    ushort_t* tbA  = (ushort_t*)(base + off); off = align(off + (size_t)(N + 1) * 64 * 2);
    ushort_t* tbB  = (ushort_t*)(base + off); off = align(off + (size_t)(N + 1) * 64 * 2);
    ushort_t* ubA  = (ushort_t*)(base + off); off = align(off + (size_t)N * 64 * 2);
    ushort_t* ubB  = (ushort_t*)(base + off); off = align(off + (size_t)N * 64 * 2);

    float* out1 = (float*)d_out;
    float* out2 = (float*)d_out + (size_t)N * 64;

    // 1) block-local bucket sort
    build_a_kernel<<<ABLK, 512, 0, stream>>>(ei, tmp, starts_m, counts_m);
    // 2) per-bucket counting sort (4-aligned) || gemm1 from x -> t1(tbA), u1(ubA)
    build_b_kernel<<<NBUK + 1024, 512, 0, stream>>>(tmp, starts_m, counts_m, row_info, csr,
                                                    x, Wrel1, Wroot1, b1, tbA, ubA);
    // 3) F1: agg1(mean) + gemm2 -> t2(tbB), u2(ubB)
    fused_kernel<<<FBLK, 256, 0, stream>>>(tbA, ubA, row_info, csr, Wnbr2, Wself2, b2,
                                           tbB, ubB, nullptr, 1);
    // 4) F2: agg2 -> out1, + gemm3 -> t3(tbA), u3(ubA)
    fused_kernel<<<FBLK, 256, 0, stream>>>(tbB, ubB, row_info, csr, Wnbr3, Wself3, b3,
                                           tbA, ubA, out1, 0);
    // 5) F3: agg3 + gemm4 -> t4(tbB), u4(ubB)
    fused_kernel<<<FBLK, 256, 0, stream>>>(tbA, ubA, row_info, csr, Wnbr4, Wself4, b4,
                                           tbB, ubB, nullptr, 0);
    // 6) F4: agg4 -> out2
    agg_kernel<<<(N + 3) / 4, 256, 0, stream>>>(tbB, ubB, row_info, csr, out2, 0);
}

// Round 11
// 336.247 us; speedup vs baseline: 1.3475x; 1.3475x over previous
//
#include <hip/hip_runtime.h>

#define N_NODES 50000
#define HIDDEN  64
#define N_EDGES 1200000

#define BSHIFT 7                       // 128 nodes per bucket
#define BUKSZ  128
#define NBUK   391                     // ceil(50000/128)
#define GBIN   256                     // scatter blocks
#define PAD2   4096                    // csr capacity per bucket (avg 3072 + 4-align pad)
#define FWAVES 12500                   // fused-layer waves (1 node per wave-iteration)
#define FBLK   (FWAVES / 4)            // 3125 blocks
#define NPW    4                       // nodes per wave (strided)

typedef unsigned short ushort_t;

__device__ __forceinline__ float bcastf(float v, int k) {
    return __int_as_float(__builtin_amdgcn_readlane(__float_as_int(v), k));
}
__device__ __forceinline__ unsigned f2bf(float x) {    // f32 -> bf16 RNE
    unsigned u = __float_as_uint(x);
    u += 0x7fffu + ((u >> 16) & 1u);
    return u >> 16;
}
__device__ __forceinline__ float bfl(unsigned w) { return __uint_as_float(w << 16); }
__device__ __forceinline__ float bfh(unsigned w) { return __uint_as_float(w & 0xffff0000u); }
__device__ __forceinline__ void bfly(float4& a) {      // all lanes end with group-sum
    a.x += __shfl_xor(a.x, 16); a.y += __shfl_xor(a.y, 16);
    a.z += __shfl_xor(a.z, 16); a.w += __shfl_xor(a.w, 16);
    a.x += __shfl_xor(a.x, 32); a.y += __shfl_xor(a.y, 32);
    a.z += __shfl_xor(a.z, 32); a.w += __shfl_xor(a.w, 32);
}

// ---------------- 1) init: cursor + W packing ----------------
// block 0: cursor init; blocks 1..3: pack W_nbr|W_self (layers 2..4) bf16-interleaved
__global__ __launch_bounds__(512) void init_kernel(int* __restrict__ cursor,
                                                   const float* __restrict__ Wn2, const float* __restrict__ Ws2,
                                                   const float* __restrict__ Wn3, const float* __restrict__ Ws3,
                                                   const float* __restrict__ Wn4, const float* __restrict__ Ws4,
                                                   uint4* __restrict__ pw) {
    int b = blockIdx.x, tid = threadIdx.x;
    if (b == 0) {
        if (tid < NBUK) cursor[tid] = tid * PAD2;
    } else {
        int layer = b - 1;
        const float* Wn = (layer == 0) ? Wn2 : (layer == 1) ? Wn3 : Wn4;
        const float* Ws = (layer == 0) ? Ws2 : (layer == 1) ? Ws3 : Ws4;
        for (int e = tid; e < 1024; e += 512) {
            const float4 a = *(const float4*)(Wn + e * 4);
            const float4 c = *(const float4*)(Ws + e * 4);
            uint4 o;
            o.x = f2bf(a.x) | (f2bf(a.y) << 16);
            o.y = f2bf(a.z) | (f2bf(a.w) << 16);
            o.z = f2bf(c.x) | (f2bf(c.y) << 16);
            o.w = f2bf(c.z) | (f2bf(c.w) << 16);
            pw[layer * 1024 + e] = o;
        }
    }
}

// ---------------- 2) scatter (R8-proven): LDS hist -> reservation -> LDS-cursor scatter ----------------
__global__ __launch_bounds__(256) void scatter_fused_kernel(const int* __restrict__ ei,
                                                            int* __restrict__ cursor,
                                                            int* __restrict__ tmp, int E) {
    __shared__ int h[NBUK];
    __shared__ int cur[NBUK];
    int tid = threadIdx.x;
    for (int b = tid; b < NBUK; b += 256) h[b] = 0;
    __syncthreads();
    for (int e = blockIdx.x * 256 + tid; e < E; e += GBIN * 256)
        atomicAdd(&h[ei[E + e] >> BSHIFT], 1);
    __syncthreads();
    for (int b = tid; b < NBUK; b += 256) cur[b] = atomicAdd(&cursor[b], h[b]);
    __syncthreads();
    for (int e = blockIdx.x * 256 + tid; e < E; e += GBIN * 256) {
        int src = ei[e];
        int dst = ei[E + e];
        int p = atomicAdd(&cur[dst >> BSHIFT], 1);
        tmp[p] = src | ((dst & (BUKSZ - 1)) << 16);
    }
}

// ---------------- 3) bucketize (R8-proven, 4-aligned) || gemm1 ----------------
__global__ __launch_bounds__(512) void bucketize_kernel(const int* __restrict__ tmp,
                                                        const int* __restrict__ cursor,
                                                        int2* __restrict__ row_info,
                                                        ushort_t* __restrict__ csr,
                                                        const float* __restrict__ x,
                                                        const float* __restrict__ Wrel,
                                                        const float* __restrict__ Wroot,
                                                        const float* __restrict__ bias,
                                                        ushort_t* __restrict__ tbf,
                                                        ushort_t* __restrict__ ubf) {
    __shared__ int hist[BUKSZ];
    __shared__ int cur[BUKSZ];
    __shared__ ushort_t stage[PAD2];
    int b = blockIdx.x, tid = threadIdx.x;
    if (b < NBUK) {
        int base = b * PAD2;
        int count = cursor[b] - base;
        int node_base = b << BSHIFT;
        if (tid < BUKSZ) hist[tid] = 0;
        __syncthreads();
        for (int i = tid; i < count; i += 512)
            atomicAdd(&hist[tmp[base + i] >> 16], 1);
        __syncthreads();
        int v = (tid < BUKSZ) ? hist[tid] : 0;
        int vr = (v + 3) & ~3;                 // 4-aligned per-node segment
        __syncthreads();
        if (tid < BUKSZ) hist[tid] = vr;
#pragma unroll
        for (int o = 1; o < BUKSZ; o <<= 1) {  // Hillis-Steele inclusive scan
            __syncthreads();
            int y = (tid >= o && tid < BUKSZ) ? hist[tid - o] : 0;
            __syncthreads();
            if (tid < BUKSZ) hist[tid] += y;
        }
        __syncthreads();
        if (tid < BUKSZ) {
            int excl = hist[tid] - vr;
            cur[tid] = excl;
            int node = node_base + tid;
            if (node < N_NODES) row_info[node] = make_int2(base + excl, v);
        }
        __syncthreads();
        for (int i = tid; i < count; i += 512) {
            int p = tmp[base + i];
            int slot = atomicAdd(&cur[p >> 16], 1);
            stage[slot] = (ushort_t)(p & 0xFFFF);
        }
        __syncthreads();
        int total = hist[BUKSZ - 1];           // rounded; pad slots garbage (clamped on use)
        for (int i = tid; i < total; i += 512)
            csr[base + i] = stage[i];
    } else {
        // gemm1: t1 = x@Wrel (bf16), u1 = x@Wroot + b1 (bf16)
        int lane = tid & 63;
        float wn[64], ws[64];
#pragma unroll
        for (int k = 0; k < 64; ++k) {
            wn[k] = Wrel[k * 64 + lane];
            ws[k] = Wroot[k * 64 + lane];
        }
        float bv = bias[lane];
        int wave = (b - NBUK) * 8 + (tid >> 6);
        int nwaves = (gridDim.x - NBUK) * 8;
        if (wave == 0) tbf[(size_t)N_NODES * 64 + lane] = 0;   // zero clamp row
        for (int i = wave; i < N_NODES; i += nwaves) {
            float hv = x[i * 64 + lane];
            float tacc = 0.f, uacc = bv;
#pragma unroll
            for (int k = 0; k < 64; ++k) {
                float hk = bcastf(hv, k);
                tacc = fmaf(hk, wn[k], tacc);
                uacc = fmaf(hk, ws[k], uacc);
            }
            tbf[(size_t)i * 64 + lane] = (ushort_t)f2bf(tacc);
            ubf[(size_t)i * 64 + lane] = (ushort_t)f2bf(uacc);
        }
    }
}

// ---------------- shfl-free gather-aggregate for one node (R8-proven) ----------------
__device__ __forceinline__ float4 agg_core(const ushort_t* __restrict__ tbf,
                                           const ushort_t* __restrict__ csr,
                                           int start, int deg, int g, int q) {
    const ushort_t* cp = csr + start;          // start is 4-aligned
    float4 a0{0,0,0,0}, a1{0,0,0,0}, a2{0,0,0,0}, a3{0,0,0,0};
    for (int base = 0; base < deg; base += 16) {
        int m = base + 4 * g;
        const uint2 iv = *(const uint2*)(cp + m);
        int s0 = (m + 0 < deg) ? (int)(iv.x & 0xFFFF) : N_NODES;
        int s1 = (m + 1 < deg) ? (int)(iv.x >> 16)    : N_NODES;
        int s2 = (m + 2 < deg) ? (int)(iv.y & 0xFFFF) : N_NODES;
        int s3 = (m + 3 < deg) ? (int)(iv.y >> 16)    : N_NODES;
        const uint2 w0 = *(const uint2*)(tbf + (size_t)s0 * 64 + q * 4);
        const uint2 w1 = *(const uint2*)(tbf + (size_t)s1 * 64 + q * 4);
        const uint2 w2 = *(const uint2*)(tbf + (size_t)s2 * 64 + q * 4);
        const uint2 w3 = *(const uint2*)(tbf + (size_t)s3 * 64 + q * 4);
        a0.x += bfl(w0.x); a0.y += bfh(w0.x); a0.z += bfl(w0.y); a0.w += bfh(w0.y);
        a1.x += bfl(w1.x); a1.y += bfh(w1.x); a1.z += bfl(w1.y); a1.w += bfh(w1.y);
        a2.x += bfl(w2.x); a2.y += bfh(w2.x); a2.z += bfl(w2.y); a2.w += bfh(w2.y);
        a3.x += bfl(w3.x); a3.y += bfh(w3.x); a3.z += bfl(w3.y); a3.w += bfh(w3.y);
    }
    float4 acc;
    acc.x = (a0.x + a1.x) + (a2.x + a3.x);
    acc.y = (a0.y + a1.y) + (a2.y + a3.y);
    acc.z = (a0.z + a1.z) + (a2.z + a3.z);
    acc.w = (a0.w + a1.w) + (a2.w + a3.w);
    bfly(acc);
    return acc;
}

__device__ __forceinline__ float4 unpack_u(const ushort_t* __restrict__ ubf, int node, int q) {
    const uint2 uv = *(const uint2*)(ubf + (size_t)node * 64 + q * 4);
    return make_float4(bfl(uv.x), bfh(uv.x), bfl(uv.y), bfh(uv.y));
}

// ---------------- fused: agg(layer k) [+ dout] + gemm(layer k+1) — R9-proven W layout ----------------
__global__ __launch_bounds__(256, 6) void fused_kernel(const ushort_t* __restrict__ tin,
                                                       const ushort_t* __restrict__ uin,
                                                       const int2* __restrict__ row_info,
                                                       const ushort_t* __restrict__ csr,
                                                       const uint4* __restrict__ pwL,
                                                       const float* __restrict__ bias_next,
                                                       ushort_t* __restrict__ tout,
                                                       ushort_t* __restrict__ uout,
                                                       float* __restrict__ dout,
                                                       int use_mean) {
    __shared__ uint4 wlds[1024];   // packed W_nbr|W_self bf16, 16 KB, linear layout (0 conflicts, R9)
    __shared__ float blds[64];
    int tid = threadIdx.x;
    for (int i = tid; i < 1024; i += 256) wlds[i] = pwL[i];
    if (tid < 64) blds[tid] = bias_next[tid];
    if (blockIdx.x == 0 && tid < 32)       // zero clamp row of tout (128 B)
        ((unsigned*)(tout + (size_t)N_NODES * 64))[tid] = 0;
    __syncthreads();
    int lane = tid & 63, g = lane >> 4, q = lane & 15;
    int w = blockIdx.x * 4 + (tid >> 6);

#pragma unroll
    for (int i = 0; i < NPW; ++i) {
        int node = w + FWAVES * i;
        if (node >= N_NODES) continue;
        int2 ri = row_info[node];
        float4 acc = agg_core(tin, csr, ri.x, ri.y, g, q);
        float sc = use_mean ? 1.f / fmaxf((float)ri.y, 1.f) : 1.f;
        const float4 uv = unpack_u(uin, node, q);
        float4 h;
        h.x = fmaxf(uv.x + acc.x * sc, 0.f);
        h.y = fmaxf(uv.y + acc.y * sc, 0.f);
        h.z = fmaxf(uv.z + acc.z * sc, 0.f);
        h.w = fmaxf(uv.w + acc.w * sc, 0.f);
        if (dout && g == 0)
            *(float4*)(dout + (size_t)node * 64 + q * 4) = h;
        // gemm: group g covers k in [16g,16g+16); h_k lives in lane 4g+(j>>2)
        float4 tp{0,0,0,0}, up{0,0,0,0};
#pragma unroll
        for (int j = 0; j < 16; ++j) {
            uint4 wv = wlds[(16 * g + j) * 16 + q];
            int srcl = 4 * g + (j >> 2);
            float hk;
            if ((j & 3) == 0)      hk = __shfl(h.x, srcl);
            else if ((j & 3) == 1) hk = __shfl(h.y, srcl);
            else if ((j & 3) == 2) hk = __shfl(h.z, srcl);
            else                   hk = __shfl(h.w, srcl);
            tp.x = fmaf(hk, bfl(wv.x), tp.x); tp.y = fmaf(hk, bfh(wv.x), tp.y);
            tp.z = fmaf(hk, bfl(wv.y), tp.z); tp.w = fmaf(hk, bfh(wv.y), tp.w);
            up.x = fmaf(hk, bfl(wv.z), up.x); up.y = fmaf(hk, bfh(wv.z), up.y);
            up.z = fmaf(hk, bfl(wv.w), up.z); up.w = fmaf(hk, bfh(wv.w), up.w);
        }
        bfly(tp); bfly(up);
        if (g == 0) {
            const float4 bv = *(const float4*)&blds[q * 4];
            uint2 upk, tpk;
            upk.x = f2bf(up.x + bv.x) | (f2bf(up.y + bv.y) << 16);
            upk.y = f2bf(up.z + bv.z) | (f2bf(up.w + bv.w) << 16);
            tpk.x = f2bf(tp.x) | (f2bf(tp.y) << 16);
            tpk.y = f2bf(tp.z) | (f2bf(tp.w) << 16);
            *(uint2*)(uout + (size_t)node * 64 + q * 4) = upk;
            *(uint2*)(tout + (size_t)node * 64 + q * 4) = tpk;
        }
    }
}

// ---------------- final agg-only (R8-proven) ----------------
__global__ __launch_bounds__(256, 8) void agg_kernel(const ushort_t* __restrict__ tbf,
                                                     const ushort_t* __restrict__ ubf,
                                                     const int2* __restrict__ row_info,
                                                     const ushort_t* __restrict__ csr,
                                                     float* __restrict__ out, int use_mean) {
    int lane = threadIdx.x & 63;
    int g = lane >> 4, q = lane & 15;
    int node = (blockIdx.x * 256 + threadIdx.x) >> 6;
    if (node >= N_NODES) return;
    int2 ri = row_info[node];
    float4 acc = agg_core(tbf, csr, ri.x, ri.y, g, q);
    float scale = use_mean ? 1.f / fmaxf((float)ri.y, 1.f) : 1.f;
    if (g == 0) {
        const float4 uv = unpack_u(ubf, node, q);
        float4 r;
        r.x = fmaxf(uv.x + acc.x * scale, 0.f);
        r.y = fmaxf(uv.y + acc.y * scale, 0.f);
        r.z = fmaxf(uv.z + acc.z * scale, 0.f);
        r.w = fmaxf(uv.w + acc.w * scale, 0.f);
        *(float4*)(out + (size_t)node * 64 + q * 4) = r;
    }
}

// ---------------- launch: 7 dispatches ----------------
extern "C" void kernel_launch(void* const* d_in, const int* in_sizes, int n_in,
                              void* d_out, int out_size, void* d_ws, size_t ws_size,
                              hipStream_t stream) {
    const float* x      = (const float*)d_in[0];
    const int*   ei     = (const int*)d_in[1];
    const float* Wrel1  = (const float*)d_in[2];
    const float* Wroot1 = (const float*)d_in[3];
    const float* b1     = (const float*)d_in[4];
    const float* Wself2 = (const float*)d_in[5];
    const float* Wnbr2  = (const float*)d_in[6];
    const float* b2     = (const float*)d_in[7];
    const float* Wself3 = (const float*)d_in[8];
    const float* Wnbr3  = (const float*)d_in[9];
    const float* b3     = (const float*)d_in[10];
    const float* Wself4 = (const float*)d_in[11];
    const float* Wnbr4  = (const float*)d_in[12];
    const float* b4     = (const float*)d_in[13];

    const int N = N_NODES, E = N_EDGES;

    auto align = [](size_t o) { return (o + 255) & ~(size_t)255; };
    char* base = (char*)d_ws;
    size_t off = 0;
    int*  cursor   = (int*)(base + off);  off = align(off + (size_t)NBUK * 4);
    int2* row_info = (int2*)(base + off); off = align(off + (size_t)N * 8);
    int*  tmp      = (int*)(base + off);  off = align(off + (size_t)NBUK * PAD2 * 4);
    ushort_t* csr  = (ushort_t*)(base + off); off = align(off + (size_t)NBUK * PAD2 * 2 + 1024);
    uint4* pw      = (uint4*)(base + off);    off = align(off + (size_t)3 * 1024 * 16);
    ushort_t* tbA  = (ushort_t*)(base + off); off = align(off + (size_t)(N + 1) * 64 * 2);
    ushort_t* tbB  = (ushort_t*)(base + off); off = align(off + (size_t)(N + 1) * 64 * 2);
    ushort_t* ubA  = (ushort_t*)(base + off); off = align(off + (size_t)N * 64 * 2);
    ushort_t* ubB  = (ushort_t*)(base + off); off = align(off + (size_t)N * 64 * 2);

    float* out1 = (float*)d_out;
    float* out2 = (float*)d_out + (size_t)N * 64;

    // 1) cursor init + W packing
    init_kernel<<<4, 512, 0, stream>>>(cursor, Wnbr2, Wself2, Wnbr3, Wself3, Wnbr4, Wself4, pw);
    // 2) bucket scatter
    scatter_fused_kernel<<<GBIN, 256, 0, stream>>>(ei, cursor, tmp, E);
    // 3) per-bucket counting sort (4-aligned) || gemm1 -> t1(tbA), u1(ubA)
    bucketize_kernel<<<NBUK + 1024, 512, 0, stream>>>(tmp, cursor, row_info, csr,
                                                      x, Wrel1, Wroot1, b1, tbA, ubA);
    // 4) F1: agg1(mean) + gemm2 -> t2(tbB), u2(ubB)
    fused_kernel<<<FBLK, 256, 0, stream>>>(tbA, ubA, row_info, csr, pw,        b2, tbB, ubB, nullptr, 1);
    // 5) F2: agg2 -> out1, + gemm3 -> t3(tbA), u3(ubA)
    fused_kernel<<<FBLK, 256, 0, stream>>>(tbB, ubB, row_info, csr, pw + 1024, b3, tbA, ubA, out1, 0);
    // 6) F3: agg3 + gemm4 -> t4(tbB), u4(ubB)
    fused_kernel<<<FBLK, 256, 0, stream>>>(tbA, ubA, row_info, csr, pw + 2048, b4, tbB, ubB, nullptr, 0);
    // 7) F4: agg4 -> out2
    agg_kernel<<<(N + 3) / 4, 256, 0, stream>>>(tbB, ubB, row_info, csr, out2, 0);
}

// Round 12
// 280.182 us; speedup vs baseline: 1.6171x; 1.2001x over previous
//
#include <hip/hip_runtime.h>
#include <hip/hip_fp16.h>

#define N_NODES 50000
#define HIDDEN  64
#define N_EDGES 1200000

#define BSHIFT 7                       // 128 nodes per bucket
#define BUKSZ  128
#define NBUK   391                     // ceil(50000/128)
#define GBIN   256                     // scatter blocks
#define PAD2   6144                    // csr capacity per bucket (avg 3072 + 16-align pads)
#define FWAVES 12500                   // fused-layer waves
#define FBLK   (FWAVES / 4)
#define NPW    4

typedef unsigned short ushort_t;
typedef _Float16 hf2 __attribute__((ext_vector_type(2)));

__device__ __forceinline__ float bcastf(float v, int k) {
    return __int_as_float(__builtin_amdgcn_readlane(__float_as_int(v), k));
}
__device__ __forceinline__ hf2 u2h(unsigned u) { union { unsigned u; hf2 h; } x; x.u = u; return x.h; }
__device__ __forceinline__ unsigned h2u(hf2 h) { union { hf2 h; unsigned u; } x; x.h = h; return x.u; }
__device__ __forceinline__ unsigned pkh(float a, float b) {   // 2xf32 -> packed f16 (v_cvt_pkrtz)
    __half2 h = __float22half2_rn(make_float2(a, b));
    union { __half2 h; unsigned u; } x; x.h = h; return x.u;
}
__device__ __forceinline__ ushort_t f2h(float a) {
    __half h = __float2half_rn(a);
    union { __half h; ushort_t u; } x; x.h = h; return x.u;
}
__device__ __forceinline__ void bfly(float4& a) {      // all lanes end with group-sum
    a.x += __shfl_xor(a.x, 16); a.y += __shfl_xor(a.y, 16);
    a.z += __shfl_xor(a.z, 16); a.w += __shfl_xor(a.w, 16);
    a.x += __shfl_xor(a.x, 32); a.y += __shfl_xor(a.y, 32);
    a.z += __shfl_xor(a.z, 32); a.w += __shfl_xor(a.w, 32);
}

// ---------------- 1) init: cursor + W f16-pair packing ----------------
// block 0: cursor; blocks 1..3: pack Wn|Ws (layers 2..4): pw[layer][kp*16+q] (Wn), +512 (Ws)
// entry = uint4 of f16 pairs (W[2kp][c], W[2kp+1][c]) for c = 4q..4q+3
__global__ __launch_bounds__(512) void init_kernel(int* __restrict__ cursor,
                                                   const float* __restrict__ Wn2, const float* __restrict__ Ws2,
                                                   const float* __restrict__ Wn3, const float* __restrict__ Ws3,
                                                   const float* __restrict__ Wn4, const float* __restrict__ Ws4,
                                                   uint4* __restrict__ pw) {
    int b = blockIdx.x, tid = threadIdx.x;
    if (b == 0) {
        if (tid < NBUK) cursor[tid] = tid * PAD2;
    } else {
        int layer = b - 1;
        const float* Wn = (layer == 0) ? Wn2 : (layer == 1) ? Wn3 : Wn4;
        const float* Ws = (layer == 0) ? Ws2 : (layer == 1) ? Ws3 : Ws4;
        int kp = tid >> 4, q = tid & 15;           // tid < 512
        {
            const float4 a = *(const float4*)(Wn + (2 * kp) * 64 + 4 * q);
            const float4 c = *(const float4*)(Wn + (2 * kp + 1) * 64 + 4 * q);
            pw[layer * 1024 + tid] = make_uint4(pkh(a.x, c.x), pkh(a.y, c.y), pkh(a.z, c.z), pkh(a.w, c.w));
        }
        {
            const float4 a = *(const float4*)(Ws + (2 * kp) * 64 + 4 * q);
            const float4 c = *(const float4*)(Ws + (2 * kp + 1) * 64 + 4 * q);
            pw[layer * 1024 + 512 + tid] = make_uint4(pkh(a.x, c.x), pkh(a.y, c.y), pkh(a.z, c.z), pkh(a.w, c.w));
        }
    }
}

// ---------------- 2) scatter (R8-proven) ----------------
__global__ __launch_bounds__(256) void scatter_fused_kernel(const int* __restrict__ ei,
                                                            int* __restrict__ cursor,
                                                            int* __restrict__ tmp, int E) {
    __shared__ int h[NBUK];
    __shared__ int cur[NBUK];
    int tid = threadIdx.x;
    for (int b = tid; b < NBUK; b += 256) h[b] = 0;
    __syncthreads();
    for (int e = blockIdx.x * 256 + tid; e < E; e += GBIN * 256)
        atomicAdd(&h[ei[E + e] >> BSHIFT], 1);
    __syncthreads();
    for (int b = tid; b < NBUK; b += 256) cur[b] = atomicAdd(&cursor[b], h[b]);
    __syncthreads();
    for (int e = blockIdx.x * 256 + tid; e < E; e += GBIN * 256) {
        int src = ei[e];
        int dst = ei[E + e];
        int p = atomicAdd(&cur[dst >> BSHIFT], 1);
        tmp[p] = src | ((dst & (BUKSZ - 1)) << 16);
    }
}

// ---------------- 3) bucketize (16-aligned, pad=50000) || gemm1 ----------------
__global__ __launch_bounds__(512) void bucketize_kernel(const int* __restrict__ tmp,
                                                        const int* __restrict__ cursor,
                                                        int2* __restrict__ row_info,
                                                        ushort_t* __restrict__ csr,
                                                        const float* __restrict__ x,
                                                        const float* __restrict__ Wrel,
                                                        const float* __restrict__ Wroot,
                                                        const float* __restrict__ bias,
                                                        ushort_t* __restrict__ tbf,
                                                        ushort_t* __restrict__ ubf) {
    __shared__ int hist[BUKSZ];
    __shared__ int cur[BUKSZ];
    __shared__ ushort_t stage[PAD2];
    int b = blockIdx.x, tid = threadIdx.x;
    if (b < NBUK) {
        int base = b * PAD2;
        int count = cursor[b] - base;
        int node_base = b << BSHIFT;
        if (tid < BUKSZ) hist[tid] = 0;
        __syncthreads();
        for (int i = tid; i < count; i += 512)
            atomicAdd(&hist[tmp[base + i] >> 16], 1);
        __syncthreads();
        int v = (tid < BUKSZ) ? hist[tid] : 0;
        int vr = (v + 15) & ~15;               // 16-aligned per-node segment (clamp-free agg)
        __syncthreads();
        if (tid < BUKSZ) hist[tid] = vr;
#pragma unroll
        for (int o = 1; o < BUKSZ; o <<= 1) {  // Hillis-Steele inclusive scan
            __syncthreads();
            int y = (tid >= o && tid < BUKSZ) ? hist[tid - o] : 0;
            __syncthreads();
            if (tid < BUKSZ) hist[tid] += y;
        }
        __syncthreads();
        int excl = 0;
        if (tid < BUKSZ) {
            excl = hist[tid] - vr;
            cur[tid] = excl;
            int node = node_base + tid;
            if (node < N_NODES) row_info[node] = make_int2(base + excl, v);
        }
        __syncthreads();
        if (tid < BUKSZ) {                     // pad slots -> zero-row index
            for (int p = v; p < vr; ++p) stage[excl + p] = (ushort_t)N_NODES;
        }
        for (int i = tid; i < count; i += 512) {
            int p = tmp[base + i];
            int slot = atomicAdd(&cur[p >> 16], 1);
            stage[slot] = (ushort_t)(p & 0xFFFF);
        }
        __syncthreads();
        int total = hist[BUKSZ - 1];
        for (int i = tid; i < total; i += 512)
            csr[base + i] = stage[i];
    } else {
        // gemm1: t1 = x@Wrel (f16), u1 = x@Wroot + b1 (f16)
        int lane = tid & 63;
        float wn[64], ws[64];
#pragma unroll
        for (int k = 0; k < 64; ++k) {
            wn[k] = Wrel[k * 64 + lane];
            ws[k] = Wroot[k * 64 + lane];
        }
        float bv = bias[lane];
        int wave = (b - NBUK) * 8 + (tid >> 6);
        int nwaves = (gridDim.x - NBUK) * 8;
        if (wave == 0) tbf[(size_t)N_NODES * 64 + lane] = 0;   // zero clamp row
        for (int i = wave; i < N_NODES; i += nwaves) {
            float hv = x[i * 64 + lane];
            float tacc = 0.f, uacc = bv;
#pragma unroll
            for (int k = 0; k < 64; ++k) {
                float hk = bcastf(hv, k);
                tacc = fmaf(hk, wn[k], tacc);
                uacc = fmaf(hk, ws[k], uacc);
            }
            tbf[(size_t)i * 64 + lane] = f2h(tacc);
            ubf[(size_t)i * 64 + lane] = f2h(uacc);
        }
    }
}

// ---------------- clamp-free f16 gather-aggregate (v_pk_add_f16 accumulate) ----------------
__device__ __forceinline__ float4 agg_core(const ushort_t* __restrict__ tbf,
                                           const ushort_t* __restrict__ csr,
                                           int start, int deg, int g, int q) {
    const ushort_t* cp = csr + start;          // start is 16-aligned, pads -> zero row
    hf2 l0{0,0}, l1{0,0}, l2{0,0}, l3{0,0};
    hf2 m0{0,0}, m1{0,0}, m2{0,0}, m3{0,0};
    int vr = (deg + 15) & ~15;
    for (int base = 0; base < vr; base += 16) {
        int m = base + 4 * g;
        const uint2 iv = *(const uint2*)(cp + m);
        int s0 = (int)(iv.x & 0xFFFF);
        int s1 = (int)(iv.x >> 16);
        int s2 = (int)(iv.y & 0xFFFF);
        int s3 = (int)(iv.y >> 16);
        const uint2 w0 = *(const uint2*)(tbf + (size_t)s0 * 64 + q * 4);
        const uint2 w1 = *(const uint2*)(tbf + (size_t)s1 * 64 + q * 4);
        const uint2 w2 = *(const uint2*)(tbf + (size_t)s2 * 64 + q * 4);
        const uint2 w3 = *(const uint2*)(tbf + (size_t)s3 * 64 + q * 4);
        l0 += u2h(w0.x); m0 += u2h(w0.y);
        l1 += u2h(w1.x); m1 += u2h(w1.y);
        l2 += u2h(w2.x); m2 += u2h(w2.y);
        l3 += u2h(w3.x); m3 += u2h(w3.y);
    }
    hf2 lo = (l0 + l1) + (l2 + l3);
    hf2 hi = (m0 + m1) + (m2 + m3);
    float4 acc = make_float4((float)lo.x, (float)lo.y, (float)hi.x, (float)hi.y);
    bfly(acc);
    return acc;
}

__device__ __forceinline__ float4 unpack_u(const ushort_t* __restrict__ ubf, int node, int q) {
    const uint2 uv = *(const uint2*)(ubf + (size_t)node * 64 + q * 4);
    hf2 a = u2h(uv.x), b = u2h(uv.y);
    return make_float4((float)a.x, (float)a.y, (float)b.x, (float)b.y);
}

// ---------------- fused: agg(layer k) [+ dout] + dot2-gemm(layer k+1) ----------------
__global__ __launch_bounds__(256, 6) void fused_kernel(const ushort_t* __restrict__ tin,
                                                       const ushort_t* __restrict__ uin,
                                                       const int2* __restrict__ row_info,
                                                       const ushort_t* __restrict__ csr,
                                                       const uint4* __restrict__ pwL,
                                                       const float* __restrict__ bias_next,
                                                       ushort_t* __restrict__ tout,
                                                       ushort_t* __restrict__ uout,
                                                       float* __restrict__ dout,
                                                       int use_mean) {
    __shared__ uint4 wlds[1024];   // [kp*16+q] Wn, +512 Ws; f16 pairs; linear (0 conflicts)
    __shared__ float blds[64];
    int tid = threadIdx.x;
    for (int i = tid; i < 1024; i += 256) wlds[i] = pwL[i];
    if (tid < 64) blds[tid] = bias_next[tid];
    if (blockIdx.x == 0 && tid < 32)       // zero clamp row of tout
        ((unsigned*)(tout + (size_t)N_NODES * 64))[tid] = 0;
    __syncthreads();
    int lane = tid & 63, g = lane >> 4, q = lane & 15;
    int w = blockIdx.x * 4 + (tid >> 6);

#pragma unroll
    for (int i = 0; i < NPW; ++i) {
        int node = w + FWAVES * i;
        if (node >= N_NODES) continue;
        int2 ri = row_info[node];
        float4 acc = agg_core(tin, csr, ri.x, ri.y, g, q);
        float sc = use_mean ? 1.f / fmaxf((float)ri.y, 1.f) : 1.f;
        const float4 uv = unpack_u(uin, node, q);
        float4 h;
        h.x = fmaxf(uv.x + acc.x * sc, 0.f);
        h.y = fmaxf(uv.y + acc.y * sc, 0.f);
        h.z = fmaxf(uv.z + acc.z * sc, 0.f);
        h.w = fmaxf(uv.w + acc.w * sc, 0.f);
        if (dout && g == 0)
            *(float4*)(dout + (size_t)node * 64 + q * 4) = h;
        // pack h into f16 k-pairs: lane q holds kp=2q (h.x,h.y) and kp=2q+1 (h.z,h.w)
        int hp_lo = (int)pkh(h.x, h.y);
        int hp_hi = (int)pkh(h.z, h.w);
        // dot2 gemm: group g covers kp in [8g, 8g+8)
        float4 tp{0,0,0,0}, up{0,0,0,0};
#pragma unroll
        for (int jp = 0; jp < 8; ++jp) {
            int kp = 8 * g + jp;
            const uint4 wvn = wlds[kp * 16 + q];
            const uint4 wvs = wlds[512 + kp * 16 + q];
            int srcl = 4 * g + (jp >> 1);
            unsigned hu = (unsigned)__shfl((jp & 1) ? hp_hi : hp_lo, srcl);
            hf2 hh = u2h(hu);
            tp.x = __builtin_amdgcn_fdot2(hh, u2h(wvn.x), tp.x, false);
            tp.y = __builtin_amdgcn_fdot2(hh, u2h(wvn.y), tp.y, false);
            tp.z = __builtin_amdgcn_fdot2(hh, u2h(wvn.z), tp.z, false);
            tp.w = __builtin_amdgcn_fdot2(hh, u2h(wvn.w), tp.w, false);
            up.x = __builtin_amdgcn_fdot2(hh, u2h(wvs.x), up.x, false);
            up.y = __builtin_amdgcn_fdot2(hh, u2h(wvs.y), up.y, false);
            up.z = __builtin_amdgcn_fdot2(hh, u2h(wvs.z), up.z, false);
            up.w = __builtin_amdgcn_fdot2(hh, u2h(wvs.w), up.w, false);
        }
        bfly(tp); bfly(up);
        if (g == 0) {
            const float4 bv = *(const float4*)&blds[q * 4];
            uint2 upk, tpk;
            upk.x = pkh(up.x + bv.x, up.y + bv.y);
            upk.y = pkh(up.z + bv.z, up.w + bv.w);
            tpk.x = pkh(tp.x, tp.y);
            tpk.y = pkh(tp.z, tp.w);
            *(uint2*)(uout + (size_t)node * 64 + q * 4) = upk;
            *(uint2*)(tout + (size_t)node * 64 + q * 4) = tpk;
        }
    }
}

// ---------------- final agg-only ----------------
__global__ __launch_bounds__(256, 8) void agg_kernel(const ushort_t* __restrict__ tbf,
                                                     const ushort_t* __restrict__ ubf,
                                                     const int2* __restrict__ row_info,
                                                     const ushort_t* __restrict__ csr,
                                                     float* __restrict__ out, int use_mean) {
    int lane = threadIdx.x & 63;
    int g = lane >> 4, q = lane & 15;
    int node = (blockIdx.x * 256 + threadIdx.x) >> 6;
    if (node >= N_NODES) return;
    int2 ri = row_info[node];
    float4 acc = agg_core(tbf, csr, ri.x, ri.y, g, q);
    float scale = use_mean ? 1.f / fmaxf((float)ri.y, 1.f) : 1.f;
    if (g == 0) {
        const float4 uv = unpack_u(ubf, node, q);
        float4 r;
        r.x = fmaxf(uv.x + acc.x * scale, 0.f);
        r.y = fmaxf(uv.y + acc.y * scale, 0.f);
        r.z = fmaxf(uv.z + acc.z * scale, 0.f);
        r.w = fmaxf(uv.w + acc.w * scale, 0.f);
        *(float4*)(out + (size_t)node * 64 + q * 4) = r;
    }
}

// ---------------- launch: 7 dispatches ----------------
extern "C" void kernel_launch(void* const* d_in, const int* in_sizes, int n_in,
                              void* d_out, int out_size, void* d_ws, size_t ws_size,
                              hipStream_t stream) {
    const float* x      = (const float*)d_in[0];
    const int*   ei     = (const int*)d_in[1];
    const float* Wrel1  = (const float*)d_in[2];
    const float* Wroot1 = (const float*)d_in[3];
    const float* b1     = (const float*)d_in[4];
    const float* Wself2 = (const float*)d_in[5];
    const float* Wnbr2  = (const float*)d_in[6];
    const float* b2     = (const float*)d_in[7];
    const float* Wself3 = (const float*)d_in[8];
    const float* Wnbr3  = (const float*)d_in[9];
    const float* b3     = (const float*)d_in[10];
    const float* Wself4 = (const float*)d_in[11];
    const float* Wnbr4  = (const float*)d_in[12];
    const float* b4     = (const float*)d_in[13];

    const int N = N_NODES, E = N_EDGES;

    auto align = [](size_t o) { return (o + 255) & ~(size_t)255; };
    char* base = (char*)d_ws;
    size_t off = 0;
    int*  cursor   = (int*)(base + off);  off = align(off + (size_t)NBUK * 4);
    int2* row_info = (int2*)(base + off); off = align(off + (size_t)N * 8);
    int*  tmp      = (int*)(base + off);  off = align(off + (size_t)NBUK * PAD2 * 4);
    ushort_t* csr  = (ushort_t*)(base + off); off = align(off + (size_t)NBUK * PAD2 * 2 + 1024);
    uint4* pw      = (uint4*)(base + off);    off = align(off + (size_t)3 * 1024 * 16);
    ushort_t* tbA  = (ushort_t*)(base + off); off = align(off + (size_t)(N + 1) * 64 * 2);
    ushort_t* tbB  = (ushort_t*)(base + off); off = align(off + (size_t)(N + 1) * 64 * 2);
    ushort_t* ubA  = (ushort_t*)(base + off); off = align(off + (size_t)N * 64 * 2);
    ushort_t* ubB  = (ushort_t*)(base + off); off = align(off + (size_t)N * 64 * 2);

    float* out1 = (float*)d_out;
    float* out2 = (float*)d_out + (size_t)N * 64;

    // 1) cursor init + W f16 packing
    init_kernel<<<4, 512, 0, stream>>>(cursor, Wnbr2, Wself2, Wnbr3, Wself3, Wnbr4, Wself4, pw);
    // 2) bucket scatter
    scatter_fused_kernel<<<GBIN, 256, 0, stream>>>(ei, cursor, tmp, E);
    // 3) per-bucket counting sort (16-aligned, zero-row pads) || gemm1 -> t1(tbA), u1(ubA)
    bucketize_kernel<<<NBUK + 1024, 512, 0, stream>>>(tmp, cursor, row_info, csr,
                                                      x, Wrel1, Wroot1, b1, tbA, ubA);
    // 4) F1: agg1(mean) + gemm2 -> t2(tbB), u2(ubB)
    fused_kernel<<<FBLK, 256, 0, stream>>>(tbA, ubA, row_info, csr, pw,        b2, tbB, ubB, nullptr, 1);
    // 5) F2: agg2 -> out1, + gemm3 -> t3(tbA), u3(ubA)
    fused_kernel<<<FBLK, 256, 0, stream>>>(tbB, ubB, row_info, csr, pw + 1024, b3, tbA, ubA, out1, 0);
    // 6) F3: agg3 + gemm4 -> t4(tbB), u4(ubB)
    fused_kernel<<<FBLK, 256, 0, stream>>>(tbA, ubA, row_info, csr, pw + 2048, b4, tbB, ubB, nullptr, 0);
    // 7) F4: agg4 -> out2
    agg_kernel<<<(N + 3) / 4, 256, 0, stream>>>(tbB, ubB, row_info, csr, out2, 0);
}